// Round 20
// baseline (613.780 us; speedup 1.0000x reference)
//
#include <hip/hip_runtime.h>
#include <hip/hip_bf16.h>
#include <math.h>

#define S_    10
#define C_    48
#define HWD   64
#define M_    512
#define PADK  4
#define PAIRS 20           // S_ * N(=2)
#define REP   32           // diagnostic repeat on k_nc and k_mm (this round)

// ws layout (float offsets)
#define OFF_GY  0                         // raw y compact fp32, c-major
#define OFF_GX  491520                    // raw x compact fp32, c-major
#define OFF_CM  983040                    // colmax (uint bits), 10240
#define OFF_MU  (OFF_CM + PAIRS * M_)     // 480 floats (channel MEANS)
#define OFF_CNT (OFF_MU + 480)            // 20 uint pair-arrival counters
#define OFF_ALL (OFF_CNT + 20)            // 1 uint pair-done counter
#define OFF_PL  (OFF_ALL + 1)             // 20 float pair losses
// fragment-major bf16: per pair 32768 ushorts (64KB). chunk(16B) = lane frag.
#define OFF_YK  993824                    // 20*32768 ushorts = 327680 floats
#define OFF_XK  (OFF_YK + 327680)         // same; end ~6.6MB

typedef __attribute__((ext_vector_type(8))) short bf16x8;
typedef __attribute__((ext_vector_type(4))) float f32x4;

__device__ __forceinline__ int gidx(int n, int c, int h, int w, int d) {
  return (((n * C_ + c) * HWD + h) * HWD + w) * HWD + d;
}

__device__ __forceinline__ unsigned short f2bf(float f) {  // RNE bf16
  unsigned u = __float_as_uint(f);
  u += 0x7FFFu + ((u >> 16) & 1u);
  return (unsigned short)(u >> 16);
}

__device__ __forceinline__ int fidx(int m, int c) {  // fragment-major ushort idx
  return ((m >> 4) << 10) + ((c >> 5) << 9) + (((c >> 3) & 3) << 7) +
         ((m & 15) << 3) + (c & 7);
}

// opaque zero: defeats cross-rep load hoisting / store collapsing (rule #17)
__device__ __forceinline__ int launder_zero() {
  int z0 = 0;
  asm volatile("" : "+v"(z0));
  return z0;
}

// ---- kernel 1: gather x,y -> compact fp32; y means; zero accumulators -----
__global__ void k_gather(const float* __restrict__ x, const float* __restrict__ y,
                         const int* __restrict__ hi, const int* __restrict__ wi,
                         const int* __restrict__ di, float* __restrict__ ws) {
  int b = blockIdx.x, t = threadIdx.x;
  int lane = t & 63, wv = t >> 6;
  __shared__ float red[4];
  if (b < 40) ws[OFF_CM + b * 256 + t] = 0.f;        // zero colmax (10240)
  if (b == 40 && t < 41) ws[OFF_CNT + t] = 0.f;      // zero CNT+ALL+PL
  int which = b >= 480;                              // 0 = y, 1 = x
  int r = which ? b - 480 : b;
  int s = r / C_, c = r % C_;
  const float* src = which ? x : y;
  int h0 = hi[s] - PADK, w0 = wi[s] - PADK, d0 = di[s] - PADK;
  float* dst = ws + (which ? OFF_GX : OFF_GY) + (s * 96 + 2 * c) * 512;
  float sum = 0.f;
#pragma unroll
  for (int j = 0; j < 4; ++j) {
    int i = t + 256 * j;
    int n = i >> 9, m = i & 511;
    float v = src[gidx(n, c, h0 + (m >> 6), w0 + ((m >> 3) & 7), d0 + (m & 7))];
    dst[n * 512 + m] = v;
    sum += v;
  }
  if (!which) {
#pragma unroll
    for (int off = 32; off; off >>= 1) sum += __shfl_xor(sum, off);
    if (lane == 0) red[wv] = sum;
    __syncthreads();
    if (t == 0)
      ws[OFF_MU + s * C_ + c] =
          (red[0] + red[1] + red[2] + red[3]) * (1.0f / 1024.0f);
  }
}

// ---- kernel 2: center + normalize -> bf16 FRAGMENT-MAJOR (xREP diag) ------
__global__ void k_nc(float* __restrict__ ws) {
  int g = blockIdx.x * 256 + threadIdx.x;   // 0..81919
  int col = g >> 2;                         // 0..20479
  int q = threadIdx.x & 3;
  int which = col >= 10240;                 // 0 = y, 1 = x
  int cix = which ? col - 10240 : col;
  int pair = cix >> 9, m = cix & 511;
  int s = pair >> 1, n = pair & 1;

  for (int rep = 0; rep < REP; ++rep) {
    int z0 = launder_zero();
    const float* base =
        ws + (which ? OFF_GX : OFF_GY) + (s * 96 + n) * 512 + m + z0;
    const float* mus = ws + OFF_MU + s * C_ + z0;
    int c0 = q * 12;
    float v[12], ss = 0.f;
#pragma unroll
    for (int j = 0; j < 12; ++j) {
      v[j] = base[(c0 + j) * 1024] - mus[c0 + j];
      ss += v[j] * v[j];
    }
    ss += __shfl_xor(ss, 1);
    ss += __shfl_xor(ss, 2);
    float sc = 1.0f / fmaxf(sqrtf(ss), 1e-12f);
    unsigned short* dstk = (unsigned short*)(ws + (which ? OFF_XK : OFF_YK)) +
                           pair * 32768 + z0;
#pragma unroll
    for (int j = 0; j < 12; ++j) dstk[fidx(m, c0 + j)] = f2bf(v[j] * sc);
    if (q == 3) {                       // zero pad k = 48..63
#pragma unroll
      for (int c = 48; c < 64; ++c) dstk[fidx(m, c)] = 0;
    }
  }
}

// ---- kernel 3: MFMA dist, frag-major coalesced (xREP diag) ----------------
__global__ __launch_bounds__(64, 2) void k_mm(float* __restrict__ ws,
                                              float* __restrict__ out) {
  int b = blockIdx.x;
  int pair = b >> 5, slab = b & 31;
  int lane = threadIdx.x;

  __shared__ unsigned arr;
  __shared__ int lastflag;

  for (int rep = 0; rep < REP; ++rep) {
    int z0 = launder_zero();
    const unsigned short* xf =
        (const unsigned short*)(ws + OFF_XK) + pair * 32768 + z0;
    const unsigned short* yf =
        (const unsigned short*)(ws + OFF_YK) + pair * 32768 + z0;

    bf16x8 a0 = *(const bf16x8*)(xf + slab * 1024 + lane * 8);
    bf16x8 a1 = *(const bf16x8*)(xf + slab * 1024 + 512 + lane * 8);

    f32x4 d[32];
#pragma unroll
    for (int ct = 0; ct < 32; ++ct) {
      bf16x8 b0 = *(const bf16x8*)(yf + ct * 1024 + lane * 8);
      bf16x8 b1 = *(const bf16x8*)(yf + ct * 1024 + 512 + lane * 8);
      f32x4 z = {0.f, 0.f, 0.f, 0.f};
      f32x4 dd = __builtin_amdgcn_mfma_f32_16x16x32_bf16(a0, b0, z, 0, 0, 0);
      d[ct] = __builtin_amdgcn_mfma_f32_16x16x32_bf16(a1, b1, dd, 0, 0, 0);
    }

    float am0 = -3.4e38f, am1 = -3.4e38f, am2 = -3.4e38f, am3 = -3.4e38f;
#pragma unroll
    for (int ct = 0; ct < 32; ++ct) {
      am0 = fmaxf(am0, d[ct][0]); am1 = fmaxf(am1, d[ct][1]);
      am2 = fmaxf(am2, d[ct][2]); am3 = fmaxf(am3, d[ct][3]);
    }
#pragma unroll
    for (int off = 1; off < 16; off <<= 1) {
      am0 = fmaxf(am0, __shfl_xor(am0, off));
      am1 = fmaxf(am1, __shfl_xor(am1, off));
      am2 = fmaxf(am2, __shfl_xor(am2, off));
      am3 = fmaxf(am3, __shfl_xor(am3, off));
    }
    float inv0 = 2.f / ((1.f - am0) + 1e-5f), c20 = 2.f - inv0;
    float inv1 = 2.f / ((1.f - am1) + 1e-5f), c21 = 2.f - inv1;
    float inv2 = 2.f / ((1.f - am2) + 1e-5f), c22 = 2.f - inv2;
    float inv3 = 2.f / ((1.f - am3) + 1e-5f), c23 = 2.f - inv3;
    float sm0 = 0.f, sm1 = 0.f, sm2 = 0.f, sm3 = 0.f;
#pragma unroll
    for (int ct = 0; ct < 32; ++ct) {
      float e0 = __expf(fmaf(d[ct][0], inv0, c20));
      float e1 = __expf(fmaf(d[ct][1], inv1, c21));
      float e2 = __expf(fmaf(d[ct][2], inv2, c22));
      float e3 = __expf(fmaf(d[ct][3], inv3, c23));
      d[ct][0] = e0; d[ct][1] = e1; d[ct][2] = e2; d[ct][3] = e3;
      sm0 += e0; sm1 += e1; sm2 += e2; sm3 += e3;
    }
#pragma unroll
    for (int off = 1; off < 16; off <<= 1) {
      sm0 += __shfl_xor(sm0, off); sm1 += __shfl_xor(sm1, off);
      sm2 += __shfl_xor(sm2, off); sm3 += __shfl_xor(sm3, off);
    }
    float rs0 = 1.f / sm0, rs1 = 1.f / sm1, rs2 = 1.f / sm2, rs3 = 1.f / sm3;
    unsigned* cmu = (unsigned*)(ws + OFF_CM) + pair * M_;
#pragma unroll
    for (int ct = 0; ct < 32; ++ct) {
      float cc = fmaxf(fmaxf(d[ct][0] * rs0, d[ct][1] * rs1),
                       fmaxf(d[ct][2] * rs2, d[ct][3] * rs3));
      cc = fmaxf(cc, __shfl_xor(cc, 16));
      cc = fmaxf(cc, __shfl_xor(cc, 32));
      if (lane < 16) atomicMax(&cmu[ct * 16 + lane], __float_as_uint(cc));
    }

    // fused final: fires at the globally LAST arrival (exactly once,
    // happens-after every block's every-rep contribution via fences).
    __threadfence();
    if (lane == 0) arr = atomicAdd((unsigned*)(ws + OFF_CNT) + pair, 1u);
    __syncthreads();
    if (arr == 32u * REP - 1u) {
      float sum = 0.f;
#pragma unroll
      for (int k = 0; k < 8; ++k)
        sum += __uint_as_float(atomicOr(&cmu[lane + 64 * k], 0u));
#pragma unroll
      for (int off = 32; off; off >>= 1) sum += __shfl_xor(sum, off);
      if (lane == 0) {
        lastflag = 0;
        float loss = -logf(sum * (1.0f / 512.0f) + 1e-5f);
        atomicExch((unsigned*)(ws + OFF_PL) + pair, __float_as_uint(loss));
        __threadfence();
        unsigned dct = atomicAdd((unsigned*)(ws + OFF_ALL), 1u);
        if (dct == PAIRS - 1) lastflag = 1;
      }
      __syncthreads();
      if (lastflag && lane < 32) {
        float v = (lane < PAIRS)
                      ? __uint_as_float(
                            atomicOr((unsigned*)(ws + OFF_PL) + lane, 0u))
                      : 0.f;
#pragma unroll
        for (int off = 16; off; off >>= 1) v += __shfl_xor(v, off);
        if (lane == 0) out[0] = v * (1.0f / (float)PAIRS);
      }
    }
  }
}

extern "C" void kernel_launch(void* const* d_in, const int* in_sizes, int n_in,
                              void* d_out, int out_size, void* d_ws, size_t ws_size,
                              hipStream_t stream) {
  const float* x = (const float*)d_in[0];
  const float* y = (const float*)d_in[1];
  const int* hi = (const int*)d_in[2];
  const int* wi = (const int*)d_in[3];
  const int* di = (const int*)d_in[4];
  float* ws = (float*)d_ws;
  float* out = (float*)d_out;

  k_gather<<<960, 256, 0, stream>>>(x, y, hi, wi, di, ws);
  k_nc<<<320, 256, 0, stream>>>(ws);
  k_mm<<<PAIRS * 32, 64, 0, stream>>>(ws, out);
}

// Round 21
// 59.025 us; speedup vs baseline: 10.3986x; 10.3986x over previous
//
#include <hip/hip_runtime.h>
#include <hip/hip_bf16.h>
#include <math.h>

#define S_    10
#define C_    48
#define HWD   64
#define M_    512
#define PADK  4
#define PAIRS 20           // S_ * N(=2)

// ws layout (float offsets)
#define OFF_GY  0                         // raw y compact fp32, c-major
#define OFF_GX  491520                    // raw x compact fp32, c-major
#define OFF_CM  983040                    // colmax (uint bits), 10240
#define OFF_MU  (OFF_CM + PAIRS * M_)     // 480 floats (channel MEANS)
#define OFF_CNT (OFF_MU + 480)            // 20 uint pair-arrival counters
#define OFF_ALL (OFF_CNT + 20)            // 1 uint pair-done counter
#define OFF_PL  (OFF_ALL + 1)             // 20 float pair losses
// fragment-major bf16: per pair 32768 ushorts (64KB). 16B chunk = lane frag.
// ushort idx(m,c) = (m>>4)*1024 + (c>>5)*512 + ((c>>3)&3)*128 + (m&15)*8 + (c&7)
#define OFF_YK  993824                    // 20*32768 ushorts = 327680 floats
#define OFF_XK  (OFF_YK + 327680)         // same; end ~6.6MB

typedef __attribute__((ext_vector_type(8))) short bf16x8;
typedef __attribute__((ext_vector_type(4))) float f32x4;

__device__ __forceinline__ int gidx(int n, int c, int h, int w, int d) {
  return (((n * C_ + c) * HWD + h) * HWD + w) * HWD + d;
}

__device__ __forceinline__ unsigned short f2bf(float f) {  // RNE bf16
  unsigned u = __float_as_uint(f);
  u += 0x7FFFu + ((u >> 16) & 1u);
  return (unsigned short)(u >> 16);
}

__device__ __forceinline__ int fidx(int m, int c) {  // fragment-major ushort idx
  return ((m >> 4) << 10) + ((c >> 5) << 9) + (((c >> 3) & 3) << 7) +
         ((m & 15) << 3) + (c & 7);
}

// ---- kernel 1: gather x,y -> compact fp32; y means; zero accumulators -----
__global__ void k_gather(const float* __restrict__ x, const float* __restrict__ y,
                         const int* __restrict__ hi, const int* __restrict__ wi,
                         const int* __restrict__ di, float* __restrict__ ws) {
  int b = blockIdx.x, t = threadIdx.x;
  int lane = t & 63, wv = t >> 6;
  __shared__ float red[4];
  if (b < 40) ws[OFF_CM + b * 256 + t] = 0.f;        // zero colmax (10240)
  if (b == 40 && t < 41) ws[OFF_CNT + t] = 0.f;      // zero CNT+ALL+PL
  int which = b >= 480;                              // 0 = y, 1 = x
  int r = which ? b - 480 : b;
  int s = r / C_, c = r % C_;
  const float* src = which ? x : y;
  int h0 = hi[s] - PADK, w0 = wi[s] - PADK, d0 = di[s] - PADK;
  float* dst = ws + (which ? OFF_GX : OFF_GY) + (s * 96 + 2 * c) * 512;
  float sum = 0.f;
#pragma unroll
  for (int j = 0; j < 4; ++j) {
    int i = t + 256 * j;
    int n = i >> 9, m = i & 511;
    float v = src[gidx(n, c, h0 + (m >> 6), w0 + ((m >> 3) & 7), d0 + (m & 7))];
    dst[n * 512 + m] = v;
    sum += v;
  }
  if (!which) {
#pragma unroll
    for (int off = 32; off; off >>= 1) sum += __shfl_xor(sum, off);
    if (lane == 0) red[wv] = sum;
    __syncthreads();
    if (t == 0)
      ws[OFF_MU + s * C_ + c] =
          (red[0] + red[1] + red[2] + red[3]) * (1.0f / 1024.0f);
  }
}

// ---- kernel 2: center + normalize -> bf16 FRAGMENT-MAJOR ------------------
__global__ void k_nc(float* __restrict__ ws) {
  int g = blockIdx.x * 256 + threadIdx.x;   // 0..81919
  int col = g >> 2;                         // 0..20479
  int q = threadIdx.x & 3;
  int which = col >= 10240;                 // 0 = y, 1 = x
  int cix = which ? col - 10240 : col;
  int pair = cix >> 9, m = cix & 511;
  int s = pair >> 1, n = pair & 1;
  const float* base = ws + (which ? OFF_GX : OFF_GY) + (s * 96 + n) * 512 + m;
  const float* mus = ws + OFF_MU + s * C_;
  int c0 = q * 12;
  float v[12], ss = 0.f;
#pragma unroll
  for (int j = 0; j < 12; ++j) {
    v[j] = base[(c0 + j) * 1024] - mus[c0 + j];
    ss += v[j] * v[j];
  }
  ss += __shfl_xor(ss, 1);
  ss += __shfl_xor(ss, 2);
  float sc = 1.0f / fmaxf(sqrtf(ss), 1e-12f);
  unsigned short* dstk = (unsigned short*)(ws + (which ? OFF_XK : OFF_YK)) +
                         pair * 32768;
#pragma unroll
  for (int j = 0; j < 12; ++j) dstk[fidx(m, c0 + j)] = f2bf(v[j] * sc);
  if (q == 3) {                         // zero pad k = 48..63
#pragma unroll
    for (int c = 48; c < 64; ++c) dstk[fidx(m, c)] = 0;
  }
}

// ---- kernel 3: MFMA dist, 4 waves/block col-split (2560 waves total) ------
// 640 blocks x 256 thr; block = (pair, slab of 16 rows); wave w owns cols
// ct = 8w..8w+7 (d[8] = 32 regs, static). Row amax/sum: in-wave 16-lane
// shuffle -> LDS [row][wave] -> float4 combine. C/D map (m89):
// col = lane&15, row = (lane>>4)*4 + reg.
__global__ __launch_bounds__(256, 2) void k_mm(float* __restrict__ ws,
                                               float* __restrict__ out) {
  int b = blockIdx.x;
  int pair = b >> 5, slab = b & 31;
  int t = threadIdx.x, lane = t & 63, wv = t >> 6;
  int kg = lane >> 4;

  __shared__ float amx[16 * 4];        // [row][wave] partial amax
  __shared__ float smx[16 * 4];        // [row][wave] partial expsum
  __shared__ float red[4];
  __shared__ unsigned arr;
  __shared__ int lastflag;

  const unsigned short* xf =
      (const unsigned short*)(ws + OFF_XK) + pair * 32768;
  const unsigned short* yf =
      (const unsigned short*)(ws + OFF_YK) + pair * 32768;

  // A-frags (same for all 4 waves; coalesced 1KB, L1/L2 hit)
  bf16x8 a0 = *(const bf16x8*)(xf + slab * 1024 + lane * 8);
  bf16x8 a1 = *(const bf16x8*)(xf + slab * 1024 + 512 + lane * 8);

  f32x4 d[8];
#pragma unroll
  for (int j = 0; j < 8; ++j) {        // 16 coalesced 1KB loads, independent
    int ct = wv * 8 + j;
    bf16x8 b0 = *(const bf16x8*)(yf + ct * 1024 + lane * 8);
    bf16x8 b1 = *(const bf16x8*)(yf + ct * 1024 + 512 + lane * 8);
    f32x4 z = {0.f, 0.f, 0.f, 0.f};
    f32x4 dd = __builtin_amdgcn_mfma_f32_16x16x32_bf16(a0, b0, z, 0, 0, 0);
    d[j] = __builtin_amdgcn_mfma_f32_16x16x32_bf16(a1, b1, dd, 0, 0, 0);
  }

  // phase 1: partial row amax over this wave's 8 cts
  float am0 = -3.4e38f, am1 = -3.4e38f, am2 = -3.4e38f, am3 = -3.4e38f;
#pragma unroll
  for (int j = 0; j < 8; ++j) {
    am0 = fmaxf(am0, d[j][0]); am1 = fmaxf(am1, d[j][1]);
    am2 = fmaxf(am2, d[j][2]); am3 = fmaxf(am3, d[j][3]);
  }
#pragma unroll
  for (int off = 1; off < 16; off <<= 1) {
    am0 = fmaxf(am0, __shfl_xor(am0, off));
    am1 = fmaxf(am1, __shfl_xor(am1, off));
    am2 = fmaxf(am2, __shfl_xor(am2, off));
    am3 = fmaxf(am3, __shfl_xor(am3, off));
  }
  if ((lane & 15) == 0) {              // one writer per (kg, wave)
    amx[(kg * 4 + 0) * 4 + wv] = am0;
    amx[(kg * 4 + 1) * 4 + wv] = am1;
    amx[(kg * 4 + 2) * 4 + wv] = am2;
    amx[(kg * 4 + 3) * 4 + wv] = am3;
  }
  __syncthreads();
  {
    float4 A0 = *(const float4*)&amx[(kg * 4 + 0) * 4];
    float4 A1 = *(const float4*)&amx[(kg * 4 + 1) * 4];
    float4 A2 = *(const float4*)&amx[(kg * 4 + 2) * 4];
    float4 A3 = *(const float4*)&amx[(kg * 4 + 3) * 4];
    am0 = fmaxf(fmaxf(A0.x, A0.y), fmaxf(A0.z, A0.w));
    am1 = fmaxf(fmaxf(A1.x, A1.y), fmaxf(A1.z, A1.w));
    am2 = fmaxf(fmaxf(A2.x, A2.y), fmaxf(A2.z, A2.w));
    am3 = fmaxf(fmaxf(A3.x, A3.y), fmaxf(A3.z, A3.w));
  }
  float inv0 = 2.f / ((1.f - am0) + 1e-5f), c20 = 2.f - inv0;
  float inv1 = 2.f / ((1.f - am1) + 1e-5f), c21 = 2.f - inv1;
  float inv2 = 2.f / ((1.f - am2) + 1e-5f), c22 = 2.f - inv2;
  float inv3 = 2.f / ((1.f - am3) + 1e-5f), c23 = 2.f - inv3;

  // phase 2: exp + partial row sums
  float sm0 = 0.f, sm1 = 0.f, sm2 = 0.f, sm3 = 0.f;
#pragma unroll
  for (int j = 0; j < 8; ++j) {        // logit = 2 - (1-a)*inv = c2 + a*inv
    float e0 = __expf(fmaf(d[j][0], inv0, c20));
    float e1 = __expf(fmaf(d[j][1], inv1, c21));
    float e2 = __expf(fmaf(d[j][2], inv2, c22));
    float e3 = __expf(fmaf(d[j][3], inv3, c23));
    d[j][0] = e0; d[j][1] = e1; d[j][2] = e2; d[j][3] = e3;
    sm0 += e0; sm1 += e1; sm2 += e2; sm3 += e3;
  }
#pragma unroll
  for (int off = 1; off < 16; off <<= 1) {
    sm0 += __shfl_xor(sm0, off); sm1 += __shfl_xor(sm1, off);
    sm2 += __shfl_xor(sm2, off); sm3 += __shfl_xor(sm3, off);
  }
  if ((lane & 15) == 0) {
    smx[(kg * 4 + 0) * 4 + wv] = sm0;
    smx[(kg * 4 + 1) * 4 + wv] = sm1;
    smx[(kg * 4 + 2) * 4 + wv] = sm2;
    smx[(kg * 4 + 3) * 4 + wv] = sm3;
  }
  __syncthreads();
  float rs0, rs1, rs2, rs3;
  {
    float4 S0 = *(const float4*)&smx[(kg * 4 + 0) * 4];
    float4 S1 = *(const float4*)&smx[(kg * 4 + 1) * 4];
    float4 S2 = *(const float4*)&smx[(kg * 4 + 2) * 4];
    float4 S3 = *(const float4*)&smx[(kg * 4 + 3) * 4];
    rs0 = 1.f / ((S0.x + S0.y) + (S0.z + S0.w));
    rs1 = 1.f / ((S1.x + S1.y) + (S1.z + S1.w));
    rs2 = 1.f / ((S2.x + S2.y) + (S2.z + S2.w));
    rs3 = 1.f / ((S3.x + S3.y) + (S3.z + S3.w));
  }

  // phase 3: colmax (max over all 16 slab rows) -> global atomic
  unsigned* cmu = (unsigned*)(ws + OFF_CM) + pair * M_;
#pragma unroll
  for (int j = 0; j < 8; ++j) {
    int ct = wv * 8 + j;
    float cc = fmaxf(fmaxf(d[j][0] * rs0, d[j][1] * rs1),
                     fmaxf(d[j][2] * rs2, d[j][3] * rs3));
    cc = fmaxf(cc, __shfl_xor(cc, 16));
    cc = fmaxf(cc, __shfl_xor(cc, 32));
    if (lane < 16) atomicMax(&cmu[ct * 16 + lane], __float_as_uint(cc));
  }

  // ---- fused final: 32 blocks/pair; last reduces; last pair writes out ---
  __threadfence();
  if (t == 0) arr = atomicAdd((unsigned*)(ws + OFF_CNT) + pair, 1u);
  __syncthreads();
  if (arr == 31) {                     // block-uniform
    float sum = __uint_as_float(atomicOr(&cmu[t], 0u)) +
                __uint_as_float(atomicOr(&cmu[t + 256], 0u));
#pragma unroll
    for (int off = 32; off; off >>= 1) sum += __shfl_xor(sum, off);
    if (lane == 0) red[wv] = sum;
    if (t == 0) lastflag = 0;
    __syncthreads();
    if (t == 0) {
      float tot = red[0] + red[1] + red[2] + red[3];
      float loss = -logf(tot * (1.0f / 512.0f) + 1e-5f);
      atomicExch((unsigned*)(ws + OFF_PL) + pair, __float_as_uint(loss));
      __threadfence();
      unsigned dct = atomicAdd((unsigned*)(ws + OFF_ALL), 1u);
      if (dct == PAIRS - 1) lastflag = 1;
    }
    __syncthreads();
    if (lastflag && t < 32) {          // parallel 20-loss readback
      float v = (t < PAIRS)
                    ? __uint_as_float(atomicOr((unsigned*)(ws + OFF_PL) + t, 0u))
                    : 0.f;
#pragma unroll
      for (int off = 16; off; off >>= 1) v += __shfl_xor(v, off);
      if (t == 0) out[0] = v * (1.0f / (float)PAIRS);
    }
  }
}

extern "C" void kernel_launch(void* const* d_in, const int* in_sizes, int n_in,
                              void* d_out, int out_size, void* d_ws, size_t ws_size,
                              hipStream_t stream) {
  const float* x = (const float*)d_in[0];
  const float* y = (const float*)d_in[1];
  const int* hi = (const int*)d_in[2];
  const int* wi = (const int*)d_in[3];
  const int* di = (const int*)d_in[4];
  float* ws = (float*)d_ws;
  float* out = (float*)d_out;

  k_gather<<<960, 256, 0, stream>>>(x, y, hi, wi, di, ws);
  k_nc<<<320, 256, 0, stream>>>(ws);
  k_mm<<<PAIRS * 32, 256, 0, stream>>>(ws, out);
}

// Round 22
// 31.961 us; speedup vs baseline: 19.2041x; 1.8468x over previous
//
#include <hip/hip_runtime.h>
#include <hip/hip_bf16.h>
#include <math.h>

#define S_    10
#define C_    48
#define HWD   64
#define M_    512
#define PADK  4
#define PAIRS 20           // S_ * N(=2)

// ws layout (float offsets)
#define OFF_GY  0                         // raw y compact fp32, c-major
#define OFF_GX  491520                    // raw x compact fp32, c-major
#define OFF_MU  983040                    // 480 floats (channel MEANS)
#define OFF_CNT (OFF_MU + 480)            // 20 uint pair-arrival counters (k_final)
#define OFF_ALL (OFF_CNT + 20)            // 1 uint pair-done counter
#define OFF_PL  (OFF_ALL + 1)             // 20 float pair losses
#define ZERO_N  (20 + 1 + 20)             // OFF_CNT..OFF_PL
// fragment-major bf16: per pair 32768 ushorts (64KB). 16B chunk = lane frag.
// ushort idx(m,c) = (m>>4)*1024 + (c>>5)*512 + ((c>>3)&3)*128 + (m&15)*8 + (c&7)
#define OFF_YK  983584                    // 20*32768 ushorts = 327680 floats
#define OFF_XK  (OFF_YK + 327680)
#define OFF_PM  (OFF_XK + 327680)         // per-block colmax: [pair][slab][512]
                                          // = 20*32*512 floats; end ~7.9MB

typedef __attribute__((ext_vector_type(8))) short bf16x8;
typedef __attribute__((ext_vector_type(4))) float f32x4;

__device__ __forceinline__ int gidx(int n, int c, int h, int w, int d) {
  return (((n * C_ + c) * HWD + h) * HWD + w) * HWD + d;
}

__device__ __forceinline__ unsigned short f2bf(float f) {  // RNE bf16
  unsigned u = __float_as_uint(f);
  u += 0x7FFFu + ((u >> 16) & 1u);
  return (unsigned short)(u >> 16);
}

__device__ __forceinline__ int fidx(int m, int c) {  // fragment-major ushort idx
  return ((m >> 4) << 10) + ((c >> 5) << 9) + (((c >> 3) & 3) << 7) +
         ((m & 15) << 3) + (c & 7);
}

// ---- kernel 1: gather x,y -> compact fp32; y means; zero final counters ---
__global__ void k_gather(const float* __restrict__ x, const float* __restrict__ y,
                         const int* __restrict__ hi, const int* __restrict__ wi,
                         const int* __restrict__ di, float* __restrict__ ws) {
  int b = blockIdx.x, t = threadIdx.x;
  int lane = t & 63, wv = t >> 6;
  __shared__ float red[4];
  if (b == 0 && t < ZERO_N) ws[OFF_CNT + t] = 0.f;   // zero CNT+ALL+PL
  int which = b >= 480;                              // 0 = y, 1 = x
  int r = which ? b - 480 : b;
  int s = r / C_, c = r % C_;
  const float* src = which ? x : y;
  int h0 = hi[s] - PADK, w0 = wi[s] - PADK, d0 = di[s] - PADK;
  float* dst = ws + (which ? OFF_GX : OFF_GY) + (s * 96 + 2 * c) * 512;
  float sum = 0.f;
#pragma unroll
  for (int j = 0; j < 4; ++j) {
    int i = t + 256 * j;
    int n = i >> 9, m = i & 511;
    float v = src[gidx(n, c, h0 + (m >> 6), w0 + ((m >> 3) & 7), d0 + (m & 7))];
    dst[n * 512 + m] = v;
    sum += v;
  }
  if (!which) {
#pragma unroll
    for (int off = 32; off; off >>= 1) sum += __shfl_xor(sum, off);
    if (lane == 0) red[wv] = sum;
    __syncthreads();
    if (t == 0)
      ws[OFF_MU + s * C_ + c] =
          (red[0] + red[1] + red[2] + red[3]) * (1.0f / 1024.0f);
  }
}

// ---- kernel 2: center + normalize -> bf16 FRAGMENT-MAJOR ------------------
__global__ void k_nc(float* __restrict__ ws) {
  int g = blockIdx.x * 256 + threadIdx.x;   // 0..81919
  int col = g >> 2;                         // 0..20479
  int q = threadIdx.x & 3;
  int which = col >= 10240;                 // 0 = y, 1 = x
  int cix = which ? col - 10240 : col;
  int pair = cix >> 9, m = cix & 511;
  int s = pair >> 1, n = pair & 1;
  const float* base = ws + (which ? OFF_GX : OFF_GY) + (s * 96 + n) * 512 + m;
  const float* mus = ws + OFF_MU + s * C_;
  int c0 = q * 12;
  float v[12], ss = 0.f;
#pragma unroll
  for (int j = 0; j < 12; ++j) {
    v[j] = base[(c0 + j) * 1024] - mus[c0 + j];
    ss += v[j] * v[j];
  }
  ss += __shfl_xor(ss, 1);
  ss += __shfl_xor(ss, 2);
  float sc = 1.0f / fmaxf(sqrtf(ss), 1e-12f);
  unsigned short* dstk = (unsigned short*)(ws + (which ? OFF_XK : OFF_YK)) +
                         pair * 32768;
#pragma unroll
  for (int j = 0; j < 12; ++j) dstk[fidx(m, c0 + j)] = f2bf(v[j] * sc);
  if (q == 3) {                         // zero pad k = 48..63
#pragma unroll
    for (int c = 48; c < 64; ++c) dstk[fidx(m, c)] = 0;
  }
}

// ---- kernel 3: MFMA dist + softmax; PLAIN-STORE slab colmax (no atomics,
//      no fences, no tail). 640 blocks x 64 thr; block = (pair, 16-row slab).
// C/D mapping per m89: col = lane&15, row = (lane>>4)*4 + reg.
__global__ __launch_bounds__(64, 2) void k_mm(float* __restrict__ ws) {
  int b = blockIdx.x;
  int pair = b >> 5, slab = b & 31;
  int lane = threadIdx.x;

  const unsigned short* xf =
      (const unsigned short*)(ws + OFF_XK) + pair * 32768;
  const unsigned short* yf =
      (const unsigned short*)(ws + OFF_YK) + pair * 32768;

  // A-frags: slab chunk, khalf 0/1 — coalesced 1KB loads
  bf16x8 a0 = *(const bf16x8*)(xf + slab * 1024 + lane * 8);
  bf16x8 a1 = *(const bf16x8*)(xf + slab * 1024 + 512 + lane * 8);

  f32x4 d[32];
#pragma unroll
  for (int ct = 0; ct < 32; ++ct) {    // 64 coalesced 1KB loads, independent
    bf16x8 b0 = *(const bf16x8*)(yf + ct * 1024 + lane * 8);
    bf16x8 b1 = *(const bf16x8*)(yf + ct * 1024 + 512 + lane * 8);
    f32x4 z = {0.f, 0.f, 0.f, 0.f};
    f32x4 dd = __builtin_amdgcn_mfma_f32_16x16x32_bf16(a0, b0, z, 0, 0, 0);
    d[ct] = __builtin_amdgcn_mfma_f32_16x16x32_bf16(a1, b1, dd, 0, 0, 0);
  }

  // epilogue: amax per row (dmin = 1 - amax) -> softmax -> slab colmax
  float am0 = -3.4e38f, am1 = -3.4e38f, am2 = -3.4e38f, am3 = -3.4e38f;
#pragma unroll
  for (int ct = 0; ct < 32; ++ct) {
    am0 = fmaxf(am0, d[ct][0]); am1 = fmaxf(am1, d[ct][1]);
    am2 = fmaxf(am2, d[ct][2]); am3 = fmaxf(am3, d[ct][3]);
  }
#pragma unroll
  for (int off = 1; off < 16; off <<= 1) {
    am0 = fmaxf(am0, __shfl_xor(am0, off));
    am1 = fmaxf(am1, __shfl_xor(am1, off));
    am2 = fmaxf(am2, __shfl_xor(am2, off));
    am3 = fmaxf(am3, __shfl_xor(am3, off));
  }
  float inv0 = 2.f / ((1.f - am0) + 1e-5f), c20 = 2.f - inv0;
  float inv1 = 2.f / ((1.f - am1) + 1e-5f), c21 = 2.f - inv1;
  float inv2 = 2.f / ((1.f - am2) + 1e-5f), c22 = 2.f - inv2;
  float inv3 = 2.f / ((1.f - am3) + 1e-5f), c23 = 2.f - inv3;
  float sm0 = 0.f, sm1 = 0.f, sm2 = 0.f, sm3 = 0.f;
#pragma unroll
  for (int ct = 0; ct < 32; ++ct) {    // logit = 2 - (1-a)*inv = c2 + a*inv
    float e0 = __expf(fmaf(d[ct][0], inv0, c20));
    float e1 = __expf(fmaf(d[ct][1], inv1, c21));
    float e2 = __expf(fmaf(d[ct][2], inv2, c22));
    float e3 = __expf(fmaf(d[ct][3], inv3, c23));
    d[ct][0] = e0; d[ct][1] = e1; d[ct][2] = e2; d[ct][3] = e3;
    sm0 += e0; sm1 += e1; sm2 += e2; sm3 += e3;
  }
#pragma unroll
  for (int off = 1; off < 16; off <<= 1) {
    sm0 += __shfl_xor(sm0, off); sm1 += __shfl_xor(sm1, off);
    sm2 += __shfl_xor(sm2, off); sm3 += __shfl_xor(sm3, off);
  }
  float rs0 = 1.f / sm0, rs1 = 1.f / sm1, rs2 = 1.f / sm2, rs3 = 1.f / sm3;
  float* pm = ws + OFF_PM + (pair * 32 + slab) * M_;
#pragma unroll
  for (int ct = 0; ct < 32; ++ct) {
    float cc = fmaxf(fmaxf(d[ct][0] * rs0, d[ct][1] * rs1),
                     fmaxf(d[ct][2] * rs2, d[ct][3] * rs3));
    cc = fmaxf(cc, __shfl_xor(cc, 16));
    cc = fmaxf(cc, __shfl_xor(cc, 32));  // max over this slab's 16 rows
    if (lane < 16) pm[ct * 16 + lane] = cc;   // plain coalesced store
  }
}

// ---- kernel 4: per-pair colmax-combine + loss; last pair writes out -------
// 20 blocks x 256 thr; block = pair. Kernel boundary = coherence for pm.
__global__ void k_final(float* __restrict__ ws, float* __restrict__ out) {
  int pair = blockIdx.x;
  int t = threadIdx.x, lane = t & 63, wv = t >> 6;
  __shared__ float red[4];
  __shared__ int lastflag;
  const float* pm = ws + OFF_PM + pair * 32 * M_;

  float m0 = 0.f, m1 = 0.f;
  for (int s = 0; s < 32; ++s) {       // coalesced: consecutive t -> consecutive
    m0 = fmaxf(m0, pm[s * M_ + t]);
    m1 = fmaxf(m1, pm[s * M_ + t + 256]);
  }
  float sum = m0 + m1;                 // per-thread partial of cx-sum
#pragma unroll
  for (int off = 32; off; off >>= 1) sum += __shfl_xor(sum, off);
  if (lane == 0) red[wv] = sum;
  if (t == 0) lastflag = 0;
  __syncthreads();
  if (t == 0) {
    float tot = red[0] + red[1] + red[2] + red[3];
    float loss = -logf(tot * (1.0f / 512.0f) + 1e-5f);
    atomicExch((unsigned*)(ws + OFF_PL) + pair, __float_as_uint(loss));
    __threadfence();
    unsigned dct = atomicAdd((unsigned*)(ws + OFF_ALL), 1u);
    if (dct == PAIRS - 1) lastflag = 1;
  }
  __syncthreads();
  if (lastflag && t < 32) {            // parallel 20-loss readback
    float v = (t < PAIRS)
                  ? __uint_as_float(atomicOr((unsigned*)(ws + OFF_PL) + t, 0u))
                  : 0.f;
#pragma unroll
    for (int off = 16; off; off >>= 1) v += __shfl_xor(v, off);
    if (t == 0) out[0] = v * (1.0f / (float)PAIRS);
  }
}

extern "C" void kernel_launch(void* const* d_in, const int* in_sizes, int n_in,
                              void* d_out, int out_size, void* d_ws, size_t ws_size,
                              hipStream_t stream) {
  const float* x = (const float*)d_in[0];
  const float* y = (const float*)d_in[1];
  const int* hi = (const int*)d_in[2];
  const int* wi = (const int*)d_in[3];
  const int* di = (const int*)d_in[4];
  float* ws = (float*)d_ws;
  float* out = (float*)d_out;

  k_gather<<<960, 256, 0, stream>>>(x, y, hi, wi, di, ws);
  k_nc<<<320, 256, 0, stream>>>(ws);
  k_mm<<<PAIRS * 32, 64, 0, stream>>>(ws);
  k_final<<<PAIRS, 256, 0, stream>>>(ws, out);
}